// Round 3
// baseline (511.246 us; speedup 1.0000x reference)
//
#include <hip/hip_runtime.h>
#include <stdint.h>

// y[8192,4096] = x[8192,4096] @ W[4096,4096]^T + bias
// W from codebook[4096,8] gathered by indices[2M].
// R7: x fp32->bf16 conversion FUSED into GEMM A-staging (reg-staged, T14):
//     - A loaded as fp32 global_load_dwordx4 one phase early, packed to bf16
//       (f2bf), ds_write_b128 into the swizzled LDS layout post-MFMA.
//     - B (W) keeps global_load_lds. Mixed-FIFO vmcnt counts re-derived:
//       P1/P3 drain with vmcnt(6) post-MFMA; end-P2/P4 fences vestigial.
//     - prep kernel is now W-dequant only (~40 MB); the 192 MB x round-trip
//       (and its kernel time) is gone.
//     GEMM counters expected: FETCH ~270 MB (A fp32), VALUBusy ~25%,
//     MfmaUtil ~46%, dur ~275 us.

#define M_DIM 8192
#define N_DIM 4096
#define K_DIM 4096
#define BM 256
#define BN 256
#define BK 64
#define NT (K_DIM / BK)                       // 64 K-tiles
#define NUM_W_BLOCKS 2097152                  // 4096*4096/8
#define PW_WGS 2048                           // W prep: 4 blocks/thread

typedef __attribute__((ext_vector_type(8))) __bf16 bf16x8;
typedef __attribute__((ext_vector_type(4))) float floatx4;

// fp32 -> bf16 round-to-nearest-even (finite inputs)
__device__ __forceinline__ unsigned int f2bf(float f) {
    unsigned int u = __builtin_bit_cast(unsigned int, f);
    u += 0x7fffu + ((u >> 16) & 1u);
    return u >> 16;
}

// ------------- prep: W dequant-gather (bf16), coalesced stores -------------
__global__ __launch_bounds__(256) void prep_kernel(
    const float* __restrict__ cb, const int* __restrict__ idx,
    uint4* __restrict__ W) {
    const int tid = threadIdx.x;
#pragma unroll
    for (int k = 0; k < 4; ++k) {
        const int b = (blockIdx.x * 4 + k) * 256 + tid;
        const int id = idx[b];
        const float4* s = (const float4*)(cb + ((size_t)id << 3));
        const float4 a = s[0];
        const float4 c = s[1];
        uint4 o;
        o.x = f2bf(a.x) | (f2bf(a.y) << 16);
        o.y = f2bf(a.z) | (f2bf(a.w) << 16);
        o.z = f2bf(c.x) | (f2bf(c.y) << 16);
        o.w = f2bf(c.z) | (f2bf(c.w) << 16);
        W[b] = o;
    }
}

// ---------------- async global -> LDS, 16B per lane (B only) --------------
__device__ __forceinline__ void async_copy16(const __bf16* g, __bf16* s) {
    __builtin_amdgcn_global_load_lds(
        (const __attribute__((address_space(1))) unsigned int*)(uintptr_t)g,
        (__attribute__((address_space(3))) unsigned int*)(uintptr_t)s,
        16, 0, 0);
}

// Stage one B unit = one k-half (256 rows x 32 bf16 = 16 KiB):
// 2 global_load_lds per thread (rows 0-127, rows 128-255).
#define STAGE_B(gsrc, slotElems)                                           \
    do {                                                                   \
        async_copy16((gsrc), sB + (slotElems) + wave512);                  \
        async_copy16((gsrc) + (size_t)128 * K_DIM,                         \
                     sB + (slotElems) + 4096 + wave512);                   \
    } while (0)

// A unit reg-load: thread's 8 fp32 of rows srow and srow+128 (4 dwordx4).
struct ALoad { floatx4 v0, v1, v2, v3; };

// ---------------- GEMM: C[M][N] = x[M][K](fp32) * W[N][K]^T + bias --------
// 512 threads = 8 waves (2M x 4N); wave owns 128x64 output = acc[8][4] f32x4.
// LDS: per operand a 4-slot ring of 16KiB k-half units: slot = (t&1)*2 + kh.
// Phases P1..P4 = (kh x mh).
//   A (x, fp32): reg-staged. setB := A(kh1,t+1) issued P1(t), written P3(t);
//                setA := A(kh0,t+2) issued P3(t), written P1(t+1).
//                Writes are post-MFMA: vmcnt(6) -> pack -> ds_write_b128.
//   B (W, bf16): global_load_lds. kh1(t+1) at P2(t), kh0(t+2) at P4(t).
// Steady per-wave FIFO at P1(t) entry: [B(kh1,t)2, setA4, B(kh0,t+1)2].
// P1 vmcnt(6) drains B(kh1,t)+setA; P3 vmcnt(6) drains B(kh0,t+1)+setB.
__global__ __launch_bounds__(512, 2) void gemm_bt_kernel(
    const float* __restrict__ A,    // [M][K] fp32 (= x)
    const __bf16* __restrict__ B,   // [N][K] bf16 (= W)
    const float* __restrict__ bias, // [N]
    float* __restrict__ C) {        // [M][N] fp32
    __shared__ __align__(16) __bf16 sA[4 * 8192];   // 64 KiB
    __shared__ __align__(16) __bf16 sB[4 * 8192];   // 64 KiB

    const int tid = threadIdx.x;
    const int wave = tid >> 6;
    const int lane = tid & 63;
    const int wr = wave >> 2;            // 0..1  (M half of tile)
    const int wc = wave & 3;             // 0..3  (N quarter of tile)

    // T1: XCD-chunked mapping (verified R6: FETCH 670->197 MB).
    const int flat = blockIdx.x;
    const int xcd = flat & 7;
    const int q = flat >> 3;             // 0..63
    const int half = q >> 5;             // 0..1
    const int sq = q & 31;
    const int m0 = ((xcd & 3) * 8 + half * 4 + (sq & 3)) * BM;
    const int n0 = ((xcd >> 2) * 8 + (sq >> 2)) * BN;

    // staging: thread t covers row = t>>2 (+128 for 2nd half), phys chunk t&3;
    // fetch logical chunk c = p ^ ((row>>1)&3) (involution, invariant +16/+128)
    const int srow = tid >> 2;
    const int schunk = ((tid & 3) ^ ((srow >> 1) & 3)) << 3;
    const float*  gA = A + (size_t)(m0 + srow) * K_DIM + schunk;  // fp32
    const __bf16* gB = B + (size_t)(n0 + srow) * K_DIM + schunk;  // bf16
    const int wave512 = wave << 9;
    const int wtid8 = tid * 8;           // thread's phys LDS elem offset

    // fragment reads: lane holds X[row = base + fr][k = (lane>>4)*8 + j];
    // physical chunk = (lane>>4) ^ ((fr>>1)&3).
    const int fr = lane & 15;
    const int roff = fr * 32 + (((lane >> 4) ^ ((fr >> 1) & 3)) << 3);
    const int aBase = wr * 4096 + roff;  // wr*128 rows * 32 elems
    const int bBase = wc * 2048 + roff;  // wc*64 rows * 32 elems

    floatx4 acc[8][4] = {};

#define LOAD_A(dst, koff)                                                  \
    do {                                                                   \
        const float* g_ = gA + (koff);                                     \
        (dst).v0 = *(const floatx4*)(g_);                                  \
        (dst).v1 = *(const floatx4*)(g_ + 4);                              \
        (dst).v2 = *(const floatx4*)(g_ + (size_t)128 * K_DIM);            \
        (dst).v3 = *(const floatx4*)(g_ + (size_t)128 * K_DIM + 4);        \
    } while (0)

#define WRITE_A(src, slotElems)                                            \
    do {                                                                   \
        uint4 o_;                                                          \
        o_.x = f2bf((src).v0.x) | (f2bf((src).v0.y) << 16);                \
        o_.y = f2bf((src).v0.z) | (f2bf((src).v0.w) << 16);                \
        o_.z = f2bf((src).v1.x) | (f2bf((src).v1.y) << 16);                \
        o_.w = f2bf((src).v1.z) | (f2bf((src).v1.w) << 16);                \
        *(uint4*)(sA + (slotElems) + wtid8) = o_;                          \
        o_.x = f2bf((src).v2.x) | (f2bf((src).v2.y) << 16);                \
        o_.y = f2bf((src).v2.z) | (f2bf((src).v2.w) << 16);                \
        o_.z = f2bf((src).v3.x) | (f2bf((src).v3.y) << 16);                \
        o_.w = f2bf((src).v3.z) | (f2bf((src).v3.w) << 16);                \
        *(uint4*)(sA + (slotElems) + 4096 + wtid8) = o_;                   \
    } while (0)

    ALoad setA, setB;

    // ---- prologue: kh0(0), kh1(0) published; kh0(1) in flight ----
    {
        ALoad p0, p1;
        LOAD_A(p0, 0);                    // A kh0 t0      (4 loads)
        LOAD_A(p1, 32);                   // A kh1 t0      (4)
        STAGE_B(gB, 0);                   // B kh0 t0      (2)
        asm volatile("s_waitcnt vmcnt(6)" ::: "memory");   // p0 done
        WRITE_A(p0, 0);
        asm volatile("s_waitcnt vmcnt(2)" ::: "memory");   // p1 done
        WRITE_A(p1, 8192);
        STAGE_B(gB + 32, 8192);           // B kh1 t0      (2)
        LOAD_A(setA, 64);                 // A kh0 t1      (4)
        STAGE_B(gB + 64, 16384);          // B kh0 t1      (2)
        asm volatile("s_waitcnt vmcnt(8)" ::: "memory");   // B kh0 t0 done
        asm volatile("s_waitcnt lgkmcnt(0)" ::: "memory"); // A writes done
        __builtin_amdgcn_s_barrier();
        // FIFO now: [B(kh1,0)2, setA(kh0,1)4, B(kh0,1)2] = steady entry.
    }

    for (int t = 0; t < NT; ++t) {
        const int cs = (t & 1) ? 16384 : 0;   // this tile's kh0 slot (elems)
        const int ns = cs ^ 16384;            // next tile's kh0 slot
        const __bf16* sA0 = sA + cs;
        const __bf16* sA1 = sA + cs + 8192;
        const __bf16* sB0 = sB + cs;
        const __bf16* sB1 = sB + cs + 8192;

        bf16x8 af[4], bfr[4];

        // ---- P1: kh0 x mh0 ; issue setB = A-kh1(t+1); post-MFMA: write
        //          setA -> kh0(t+1) slot (vmcnt(6) drains B(kh1,t)+setA)
#pragma unroll
        for (int i = 0; i < 4; ++i)
            af[i] = *(const bf16x8*)(sA0 + aBase + i * 512);
#pragma unroll
        for (int j = 0; j < 4; ++j)
            bfr[j] = *(const bf16x8*)(sB0 + bBase + j * 512);
        if (t + 1 < NT) { LOAD_A(setB, (size_t)(t + 1) * 64 + 32); }
        __builtin_amdgcn_s_barrier();
        asm volatile("s_waitcnt lgkmcnt(0)" ::: "memory");
        __builtin_amdgcn_s_setprio(1);
#pragma unroll
        for (int i = 0; i < 4; ++i)
#pragma unroll
            for (int j = 0; j < 4; ++j)
                acc[i][j] = __builtin_amdgcn_mfma_f32_16x16x32_bf16(
                    af[i], bfr[j], acc[i][j], 0, 0, 0);
        __builtin_amdgcn_s_setprio(0);
        if (t + 1 < NT) {
            asm volatile("s_waitcnt vmcnt(6)" ::: "memory");
            WRITE_A(setA, ns);            // kh0(t+1); WAR-safe: last readers
        }                                 // were P1/P2(t-1), long done.
        __builtin_amdgcn_s_barrier();

        // ---- P2: kh0 x mh1 ; stage B-kh1(t+1)
#pragma unroll
        for (int i = 0; i < 4; ++i)
            af[i] = *(const bf16x8*)(sA0 + aBase + 2048 + i * 512);
        if (t + 1 < NT) { STAGE_B(gB + (size_t)(t + 1) * 64 + 32, ns + 8192); }
        __builtin_amdgcn_s_barrier();
        asm volatile("s_waitcnt lgkmcnt(0)" ::: "memory");
        __builtin_amdgcn_s_setprio(1);
#pragma unroll
        for (int i = 0; i < 4; ++i)
#pragma unroll
            for (int j = 0; j < 4; ++j)
                acc[i + 4][j] = __builtin_amdgcn_mfma_f32_16x16x32_bf16(
                    af[i], bfr[j], acc[i + 4][j], 0, 0, 0);
        __builtin_amdgcn_s_setprio(0);
        if (t + 1 < NT)
            asm volatile("s_waitcnt vmcnt(8)" ::: "memory");  // vestigial
        else
            asm volatile("s_waitcnt vmcnt(0)" ::: "memory");  // drain tail
        __builtin_amdgcn_s_barrier();

        // ---- P3: kh1 x mh0 ; issue setA = A-kh0(t+2); post-MFMA: write
        //          setB -> kh1(t+1) slot (vmcnt drains B(kh0,t+1)+setB)
#pragma unroll
        for (int i = 0; i < 4; ++i)
            af[i] = *(const bf16x8*)(sA1 + aBase + i * 512);
#pragma unroll
        for (int j = 0; j < 4; ++j)
            bfr[j] = *(const bf16x8*)(sB1 + bBase + j * 512);
        if (t + 2 < NT) { LOAD_A(setA, (size_t)(t + 2) * 64); }
        __builtin_amdgcn_s_barrier();
        asm volatile("s_waitcnt lgkmcnt(0)" ::: "memory");
        __builtin_amdgcn_s_setprio(1);
#pragma unroll
        for (int i = 0; i < 4; ++i)
#pragma unroll
            for (int j = 0; j < 4; ++j)
                acc[i][j] = __builtin_amdgcn_mfma_f32_16x16x32_bf16(
                    af[i], bfr[j], acc[i][j], 0, 0, 0);
        __builtin_amdgcn_s_setprio(0);
        if (t + 1 < NT) {
            if (t + 2 < NT)
                asm volatile("s_waitcnt vmcnt(6)" ::: "memory");
            else
                asm volatile("s_waitcnt vmcnt(2)" ::: "memory");
            WRITE_A(setB, ns + 8192);     // kh1(t+1); WAR-safe (P3/P4(t-1)).
        }
        __builtin_amdgcn_s_barrier();

        // ---- P4: kh1 x mh1 ; stage B-kh0(t+2)
#pragma unroll
        for (int i = 0; i < 4; ++i)
            af[i] = *(const bf16x8*)(sA1 + aBase + 2048 + i * 512);
        if (t + 2 < NT) { STAGE_B(gB + (size_t)(t + 2) * 64, cs); }
        __builtin_amdgcn_s_barrier();
        asm volatile("s_waitcnt lgkmcnt(0)" ::: "memory");
        __builtin_amdgcn_s_setprio(1);
#pragma unroll
        for (int i = 0; i < 4; ++i)
#pragma unroll
            for (int j = 0; j < 4; ++j)
                acc[i + 4][j] = __builtin_amdgcn_mfma_f32_16x16x32_bf16(
                    af[i], bfr[j], acc[i + 4][j], 0, 0, 0);
        __builtin_amdgcn_s_setprio(0);
        if (t + 2 < NT)
            asm volatile("s_waitcnt vmcnt(8)" ::: "memory");  // vestigial
        else if (t + 1 < NT)
            asm volatile("s_waitcnt vmcnt(2)" ::: "memory");
        else
            asm volatile("s_waitcnt vmcnt(0)" ::: "memory");
        __builtin_amdgcn_s_barrier();
    }

    // Epilogue. C/D layout: col = lane&15, row = (lane>>4)*4 + reg
    const int crow = (lane >> 4) * 4;
    const int ccol = lane & 15;
#pragma unroll
    for (int j = 0; j < 4; ++j) {
        const int n = n0 + wc * 64 + j * 16 + ccol;
        const float bv = bias[n];
#pragma unroll
        for (int i = 0; i < 8; ++i) {
            const int m = m0 + wr * 128 + i * 16 + crow;
            float* cp = C + (size_t)m * N_DIM + n;
#pragma unroll
            for (int r = 0; r < 4; ++r)
                __builtin_nontemporal_store(acc[i][j][r] + bv,
                                            cp + (size_t)r * N_DIM);
        }
    }
#undef LOAD_A
#undef WRITE_A
}

extern "C" void kernel_launch(void* const* d_in, const int* in_sizes, int n_in,
                              void* d_out, int out_size, void* d_ws, size_t ws_size,
                              hipStream_t stream) {
    const float* x    = (const float*)d_in[0];   // [4,2048,4096] fp32
    const float* cb   = (const float*)d_in[1];   // [4096,8] fp32
    const int*   idx  = (const int*)d_in[2];     // [2M]
    const float* bias = (const float*)d_in[3];   // [4096]
    float* out = (float*)d_out;                  // [4,2048,4096] fp32

    // workspace: W_bf16 (32 MB) only — x round-trip eliminated.
    __bf16* Wb = (__bf16*)d_ws;

    prep_kernel<<<PW_WGS, 256, 0, stream>>>(cb, idx, (uint4*)Wb);

    dim3 grid(M_DIM / BM * (N_DIM / BN));  // 512 WGs, XCD-chunked in-kernel
    gemm_bt_kernel<<<grid, 512, 0, stream>>>(x, Wb, bias, out);
}

// Round 4
// 477.289 us; speedup vs baseline: 1.0711x; 1.0711x over previous
//
#include <hip/hip_runtime.h>
#include <stdint.h>

// y[8192,4096] = x[8192,4096] @ W[4096,4096]^T + bias
// W from codebook[4096,8] gathered by indices[2M].
// R8: revert R7 fusion (GEMM 363->268 path). Split design:
//     - prep: W dequant (R7's verified kernel) + x fp32->bf16 pass, one launch.
//     - GEMM: R6 base, phases merged 4 -> 2 per K-tile (one per k-half,
//       full 256-row m extent): 12 ds_read_b128 + 32-MFMA cluster per phase,
//       4 barriers/tile (was 8). vmcnt fences now real counted drains:
//       steady 12 outstanding, vmcnt(8) at end of each phase.

#define M_DIM 8192
#define N_DIM 4096
#define K_DIM 4096
#define BM 256
#define BN 256
#define BK 64
#define NT (K_DIM / BK)                       // 64 K-tiles
#define NUM_W_BLOCKS 2097152                  // 4096*4096/8

// prep geometry
#define PW_WGS 2048                           // W: 4 blocks/thread
#define PX_WGS 4096                           // X: 4 x (32B load, 16B store)/thread
#define PX_OUT (M_DIM * K_DIM / 8)            // 4,194,304 uint4 outs
#define PX_ITERS (PX_OUT / (PX_WGS * 256))    // 4

typedef __attribute__((ext_vector_type(8))) __bf16 bf16x8;
typedef __attribute__((ext_vector_type(4))) float floatx4;

// fp32 -> bf16 round-to-nearest-even (finite inputs)
__device__ __forceinline__ unsigned int f2bf(float f) {
    unsigned int u = __builtin_bit_cast(unsigned int, f);
    u += 0x7fffu + ((u >> 16) & 1u);
    return u >> 16;
}

// ------------- prep: W dequant-gather + x fp32->bf16 -------------
__global__ __launch_bounds__(256) void prep_kernel(
    const float* __restrict__ cb, const int* __restrict__ idx,
    uint4* __restrict__ W, const float4* __restrict__ x4,
    uint4* __restrict__ xb4) {
    const int wg = blockIdx.x;
    const int tid = threadIdx.x;
    if (wg < PW_WGS) {
#pragma unroll
        for (int k = 0; k < 4; ++k) {
            const int b = (wg * 4 + k) * 256 + tid;
            const int id = idx[b];
            const float4* s = (const float4*)(cb + ((size_t)id << 3));
            const float4 a = s[0];
            const float4 c = s[1];
            uint4 o;
            o.x = f2bf(a.x) | (f2bf(a.y) << 16);
            o.y = f2bf(a.z) | (f2bf(a.w) << 16);
            o.z = f2bf(c.x) | (f2bf(c.y) << 16);
            o.w = f2bf(c.z) | (f2bf(c.w) << 16);
            W[b] = o;
        }
    } else {
        const int xwg = wg - PW_WGS;
#pragma unroll
        for (int it = 0; it < PX_ITERS; ++it) {
            const size_t o = ((size_t)(it * PX_WGS + xwg)) * 256 + tid;
            const float4 a = x4[2 * o];
            const float4 c = x4[2 * o + 1];
            uint4 v;
            v.x = f2bf(a.x) | (f2bf(a.y) << 16);
            v.y = f2bf(a.z) | (f2bf(a.w) << 16);
            v.z = f2bf(c.x) | (f2bf(c.y) << 16);
            v.w = f2bf(c.z) | (f2bf(c.w) << 16);
            xb4[o] = v;
        }
    }
}

// ---------------- async global -> LDS, 16B per lane ----------------
__device__ __forceinline__ void async_copy16(const __bf16* g, __bf16* s) {
    __builtin_amdgcn_global_load_lds(
        (const __attribute__((address_space(1))) unsigned int*)(uintptr_t)g,
        (__attribute__((address_space(3))) unsigned int*)(uintptr_t)s,
        16, 0, 0);
}

// Stage one unit = one operand k-half (256 rows x 32 bf16 = 16 KiB):
// 2 global_load_lds per thread (rows 0-127, rows 128-255).
#define STAGE(gsrc, arr, slotElems)                                        \
    do {                                                                   \
        async_copy16((gsrc), (arr) + (slotElems) + wave512);               \
        async_copy16((gsrc) + (size_t)128 * K_DIM,                         \
                     (arr) + (slotElems) + 4096 + wave512);                \
    } while (0)

// ---------------- GEMM: C[M][N] = A[M][K] * B[N][K]^T + bias ----------------
// 512 threads = 8 waves (2M x 4N); wave owns 128x64 output = acc[8][4] f32x4.
// LDS: per operand a 4-slot ring of 16KiB k-half units: slot = (t&1)*2 + kh.
// 2 phases per K-tile (A: kh0, B: kh1), each: 12 ds_read_b128 (af0,bf,af1)
// + stage next k-half pair -> barrier -> 32 MFMA -> counted vmcnt -> barrier.
// Steady FIFO (2-load units): at end-A outstanding = [kh1(t)4, kh0(t+1)4,
// kh1(t+1)4] -> vmcnt(8) drains kh1(t); at end-B = [kh0(t+1)4, kh1(t+1)4,
// kh0(t+2)4] -> vmcnt(8) drains kh0(t+1).
__global__ __launch_bounds__(512, 2) void gemm_bt_kernel(
    const __bf16* __restrict__ A,   // [M][K] bf16
    const __bf16* __restrict__ B,   // [N][K] bf16
    const float* __restrict__ bias, // [N]
    float* __restrict__ C) {        // [M][N] fp32
    __shared__ __align__(16) __bf16 sA[4 * 8192];   // 64 KiB
    __shared__ __align__(16) __bf16 sB[4 * 8192];   // 64 KiB

    const int tid = threadIdx.x;
    const int wave = tid >> 6;
    const int lane = tid & 63;
    const int wr = wave >> 2;            // 0..1  (M half of tile)
    const int wc = wave & 3;             // 0..3  (N quarter of tile)

    // T1: XCD-chunked mapping (verified R6: FETCH 670->197 MB).
    const int flat = blockIdx.x;
    const int xcd = flat & 7;
    const int q = flat >> 3;             // 0..63
    const int half = q >> 5;             // 0..1
    const int sq = q & 31;
    const int m0 = ((xcd & 3) * 8 + half * 4 + (sq & 3)) * BM;
    const int n0 = ((xcd >> 2) * 8 + (sq >> 2)) * BN;

    // staging: thread t covers row = t>>2 (+128 for 2nd half), phys chunk t&3;
    // fetch logical chunk c = p ^ ((row>>1)&3) (involution, invariant +16/+128)
    const int srow = tid >> 2;
    const int schunk = ((tid & 3) ^ ((srow >> 1) & 3)) << 3;
    const __bf16* gA = A + (size_t)(m0 + srow) * K_DIM + schunk;
    const __bf16* gB = B + (size_t)(n0 + srow) * K_DIM + schunk;
    const int wave512 = wave << 9;

    // fragment reads: lane holds X[row = base + fr][k = (lane>>4)*8 + j];
    // physical chunk = (lane>>4) ^ ((fr>>1)&3).
    const int fr = lane & 15;
    const int roff = fr * 32 + (((lane >> 4) ^ ((fr >> 1) & 3)) << 3);
    const int aBase = wr * 4096 + roff;  // wr*128 rows * 32 elems
    const int bBase = wc * 2048 + roff;  // wc*64 rows * 32 elems

    floatx4 acc[8][4] = {};

    // ---- prologue: kh0(0), kh1(0), kh0(1) staged in FIFO order ----
    STAGE(gA, sA, 0);             // A kh0 t0 -> slot 0
    STAGE(gB, sB, 0);
    STAGE(gA + 32, sA, 8192);     // A kh1 t0 -> slot 1
    STAGE(gB + 32, sB, 8192);
    STAGE(gA + 64, sA, 16384);    // A kh0 t1 -> slot 2
    STAGE(gB + 64, sB, 16384);
    asm volatile("s_waitcnt vmcnt(8)" ::: "memory");  // kh0(0) landed
    __builtin_amdgcn_s_barrier();

    for (int t = 0; t < NT; ++t) {
        const int cs = (t & 1) ? 16384 : 0;   // this tile's kh0 slot (elems)
        const int ns = cs ^ 16384;            // next tile's kh0 slot
        const __bf16* sA0 = sA + cs;
        const __bf16* sA1 = sA + cs + 8192;
        const __bf16* sB0 = sB + cs;
        const __bf16* sB1 = sB + cs + 8192;

        bf16x8 af0[4], af1[4], bfr[4];

        // ======== Phase A: kh0 x (mh0+mh1) ; stage kh1(t+1) pair ========
#pragma unroll
        for (int i = 0; i < 4; ++i)
            af0[i] = *(const bf16x8*)(sA0 + aBase + i * 512);
#pragma unroll
        for (int j = 0; j < 4; ++j)
            bfr[j] = *(const bf16x8*)(sB0 + bBase + j * 512);
#pragma unroll
        for (int i = 0; i < 4; ++i)
            af1[i] = *(const bf16x8*)(sA0 + aBase + 2048 + i * 512);
        if (t + 1 < NT) {
            STAGE(gA + (size_t)(t + 1) * 64 + 32, sA, ns + 8192);
            STAGE(gB + (size_t)(t + 1) * 64 + 32, sB, ns + 8192);
        }
        __builtin_amdgcn_s_barrier();
        asm volatile("s_waitcnt lgkmcnt(0)" ::: "memory");
        __builtin_amdgcn_s_setprio(1);
#pragma unroll
        for (int i = 0; i < 4; ++i)
#pragma unroll
            for (int j = 0; j < 4; ++j)
                acc[i][j] = __builtin_amdgcn_mfma_f32_16x16x32_bf16(
                    af0[i], bfr[j], acc[i][j], 0, 0, 0);
#pragma unroll
        for (int i = 0; i < 4; ++i)
#pragma unroll
            for (int j = 0; j < 4; ++j)
                acc[i + 4][j] = __builtin_amdgcn_mfma_f32_16x16x32_bf16(
                    af1[i], bfr[j], acc[i + 4][j], 0, 0, 0);
        __builtin_amdgcn_s_setprio(0);
        // drain kh1(t) (staged in phase A of t-1 / prologue)
        if (t + 1 < NT)
            asm volatile("s_waitcnt vmcnt(8)" ::: "memory");
        else
            asm volatile("s_waitcnt vmcnt(0)" ::: "memory");
        __builtin_amdgcn_s_barrier();

        // ======== Phase B: kh1 x (mh0+mh1) ; stage kh0(t+2) pair ========
#pragma unroll
        for (int i = 0; i < 4; ++i)
            af0[i] = *(const bf16x8*)(sA1 + aBase + i * 512);
#pragma unroll
        for (int j = 0; j < 4; ++j)
            bfr[j] = *(const bf16x8*)(sB1 + bBase + j * 512);
#pragma unroll
        for (int i = 0; i < 4; ++i)
            af1[i] = *(const bf16x8*)(sA1 + aBase + 2048 + i * 512);
        if (t + 2 < NT) {
            STAGE(gA + (size_t)(t + 2) * 64, sA, cs);
            STAGE(gB + (size_t)(t + 2) * 64, sB, cs);
        }
        __builtin_amdgcn_s_barrier();
        asm volatile("s_waitcnt lgkmcnt(0)" ::: "memory");
        __builtin_amdgcn_s_setprio(1);
#pragma unroll
        for (int i = 0; i < 4; ++i)
#pragma unroll
            for (int j = 0; j < 4; ++j)
                acc[i][j] = __builtin_amdgcn_mfma_f32_16x16x32_bf16(
                    af0[i], bfr[j], acc[i][j], 0, 0, 0);
#pragma unroll
        for (int i = 0; i < 4; ++i)
#pragma unroll
            for (int j = 0; j < 4; ++j)
                acc[i + 4][j] = __builtin_amdgcn_mfma_f32_16x16x32_bf16(
                    af1[i], bfr[j], acc[i + 4][j], 0, 0, 0);
        __builtin_amdgcn_s_setprio(0);
        // drain kh0(t+1) (staged in phase B of t-1 / prologue)
        if (t + 2 < NT)
            asm volatile("s_waitcnt vmcnt(8)" ::: "memory");
        else if (t + 1 < NT)
            asm volatile("s_waitcnt vmcnt(4)" ::: "memory");
        else
            asm volatile("s_waitcnt vmcnt(0)" ::: "memory");
        __builtin_amdgcn_s_barrier();
    }

    // Epilogue. C/D layout: col = lane&15, row = (lane>>4)*4 + reg
    const int crow = (lane >> 4) * 4;
    const int ccol = lane & 15;
#pragma unroll
    for (int j = 0; j < 4; ++j) {
        const int n = n0 + wc * 64 + j * 16 + ccol;
        const float bv = bias[n];
#pragma unroll
        for (int i = 0; i < 8; ++i) {
            const int m = m0 + wr * 128 + i * 16 + crow;
            float* cp = C + (size_t)m * N_DIM + n;
#pragma unroll
            for (int r = 0; r < 4; ++r)
                __builtin_nontemporal_store(acc[i][j][r] + bv,
                                            cp + (size_t)r * N_DIM);
        }
    }
}

extern "C" void kernel_launch(void* const* d_in, const int* in_sizes, int n_in,
                              void* d_out, int out_size, void* d_ws, size_t ws_size,
                              hipStream_t stream) {
    const float* x    = (const float*)d_in[0];   // [4,2048,4096] fp32
    const float* cb   = (const float*)d_in[1];   // [4096,8] fp32
    const int*   idx  = (const int*)d_in[2];     // [2M]
    const float* bias = (const float*)d_in[3];   // [4096]
    float* out = (float*)d_out;                  // [4,2048,4096] fp32

    // workspace layout: W_bf16 (32 MB) | x_bf16 (64 MB)
    __bf16* Wb = (__bf16*)d_ws;
    __bf16* Xb = (__bf16*)((char*)d_ws + (size_t)N_DIM * K_DIM * sizeof(__bf16));

    prep_kernel<<<PW_WGS + PX_WGS, 256, 0, stream>>>(
        cb, idx, (uint4*)Wb, (const float4*)x, (uint4*)Xb);

    dim3 grid(M_DIM / BM * (N_DIM / BN));  // 512 WGs, XCD-chunked in-kernel
    gemm_bt_kernel<<<grid, 512, 0, stream>>>(Xb, Wb, bias, out);
}

// Round 5
// 460.494 us; speedup vs baseline: 1.1102x; 1.0365x over previous
//
#include <hip/hip_runtime.h>
#include <stdint.h>

// y[8192,4096] = x[8192,4096] @ W[4096,4096]^T + bias
// W from codebook[4096,8] gathered by indices[2M].
// R9: (a) GEMM: remove the pre-MFMA barrier in each phase (1 barrier/phase).
//         Hazard-checked: publication = prev phase's vmcnt(8)+barrier; WAR =
//         reads complete before closing barrier, STAGE issued after it.
//         Waves now desync within a phase -> LDS-read bursts of one wave
//         overlap MFMA of another (the missing ~50% -> ~65% lever).
//         Compiler-managed partial lgkmcnt (no explicit lgkm drain);
//         STAGE issued before frag reads for extra DMA latency cover.
//     (b) prep reverted to R5 one-shot grid (measured-best residual).

#define M_DIM 8192
#define N_DIM 4096
#define K_DIM 4096
#define BM 256
#define BN 256
#define BK 64
#define NT (K_DIM / BK)                       // 64 K-tiles
#define NUM_W_BLOCKS 2097152                  // 4096*4096/8
#define W_WGS (NUM_W_BLOCKS / 256)            // 8192 WGs for W dequant
#define X_WGS ((M_DIM * K_DIM / 4) / 256)     // 32768 WGs, one float4/thread

typedef __attribute__((ext_vector_type(8))) __bf16 bf16x8;
typedef __attribute__((ext_vector_type(4))) float floatx4;
typedef __attribute__((ext_vector_type(2))) unsigned int uintx2;

// fp32 -> bf16 round-to-nearest-even (finite inputs)
__device__ __forceinline__ unsigned int f2bf(float f) {
    unsigned int u = __builtin_bit_cast(unsigned int, f);
    u += 0x7fffu + ((u >> 16) & 1u);
    return u >> 16;
}

// ------------- fused prep: W dequant-gather + x fp32->bf16 -------------
// One-shot: WGs [0, W_WGS): one codebook block (8 elems) per thread.
//           WGs [W_WGS, W_WGS+X_WGS): one float4 per thread.
__global__ __launch_bounds__(256) void prep_kernel(
    const float* __restrict__ cb, const int* __restrict__ idx,
    uint4* __restrict__ W, const floatx4* __restrict__ x,
    uintx2* __restrict__ xb) {
    const int wg = blockIdx.x;
    if (wg < W_WGS) {
        const int b = wg * 256 + threadIdx.x;
        const int id = __builtin_nontemporal_load(idx + b);
        const float4* s = (const float4*)(cb + ((size_t)id << 3));
        const float4 a = s[0];
        const float4 c = s[1];
        uint4 o;
        o.x = f2bf(a.x) | (f2bf(a.y) << 16);
        o.y = f2bf(a.z) | (f2bf(a.w) << 16);
        o.z = f2bf(c.x) | (f2bf(c.y) << 16);
        o.w = f2bf(c.z) | (f2bf(c.w) << 16);
        W[b] = o;
    } else {
        const size_t t = (size_t)(wg - W_WGS) * 256 + threadIdx.x;
        const floatx4 a = __builtin_nontemporal_load(x + t);
        uintx2 o;
        o.x = f2bf(a.x) | (f2bf(a.y) << 16);
        o.y = f2bf(a.z) | (f2bf(a.w) << 16);
        xb[t] = o;
    }
}

// ---------------- async global -> LDS, 16B per lane ----------------
__device__ __forceinline__ void async_copy16(const __bf16* g, __bf16* s) {
    __builtin_amdgcn_global_load_lds(
        (const __attribute__((address_space(1))) unsigned int*)(uintptr_t)g,
        (__attribute__((address_space(3))) unsigned int*)(uintptr_t)s,
        16, 0, 0);
}

// Stage one unit = one operand k-half (256 rows x 32 bf16 = 16 KiB):
// 2 global_load_lds per thread (rows 0-127, rows 128-255).
#define STAGE(gsrc, arr, slotElems)                                        \
    do {                                                                   \
        async_copy16((gsrc), (arr) + (slotElems) + wave512);               \
        async_copy16((gsrc) + (size_t)128 * K_DIM,                         \
                     (arr) + (slotElems) + 4096 + wave512);                \
    } while (0)

// ---------------- GEMM: C[M][N] = A[M][K] * B[N][K]^T + bias ----------------
// 512 threads = 8 waves (2M x 4N); wave owns 128x64 output = acc[8][4] f32x4.
// LDS: per operand a 4-slot ring of 16KiB k-half units: slot = (t&1)*2 + kh.
// 2 phases per K-tile, ONE barrier per phase (at phase end):
//   phase = [STAGE next unit pair] [12 ds_read_b128] [32 MFMA, compiler
//            partial-lgkm] [counted vmcnt drain] [s_barrier]
// Publication: unit staged in phase P is drained by vmcnt(8) at end of the
// phase BEFORE its consumer, + that phase's barrier (all waves drained).
// WAR: a slot's readers all finish before the phase-closing barrier; the
// overwriting STAGE is issued after it. Waves desync < 1 phase.
__global__ __launch_bounds__(512, 2) void gemm_bt_kernel(
    const __bf16* __restrict__ A,   // [M][K] bf16
    const __bf16* __restrict__ B,   // [N][K] bf16
    const float* __restrict__ bias, // [N]
    float* __restrict__ C) {        // [M][N] fp32
    __shared__ __align__(16) __bf16 sA[4 * 8192];   // 64 KiB
    __shared__ __align__(16) __bf16 sB[4 * 8192];   // 64 KiB

    const int tid = threadIdx.x;
    const int wave = tid >> 6;
    const int lane = tid & 63;
    const int wr = wave >> 2;            // 0..1  (M half of tile)
    const int wc = wave & 3;             // 0..3  (N quarter of tile)

    // T1: XCD-chunked mapping (verified R6: FETCH 670->197 MB).
    const int flat = blockIdx.x;
    const int xcd = flat & 7;
    const int q = flat >> 3;             // 0..63
    const int half = q >> 5;             // 0..1
    const int sq = q & 31;
    const int m0 = ((xcd & 3) * 8 + half * 4 + (sq & 3)) * BM;
    const int n0 = ((xcd >> 2) * 8 + (sq >> 2)) * BN;

    // staging: thread t covers row = t>>2 (+128 for 2nd half), phys chunk t&3;
    // fetch logical chunk c = p ^ ((row>>1)&3) (involution, invariant +16/+128)
    const int srow = tid >> 2;
    const int schunk = ((tid & 3) ^ ((srow >> 1) & 3)) << 3;
    const __bf16* gA = A + (size_t)(m0 + srow) * K_DIM + schunk;
    const __bf16* gB = B + (size_t)(n0 + srow) * K_DIM + schunk;
    const int wave512 = wave << 9;

    // fragment reads: lane holds X[row = base + fr][k = (lane>>4)*8 + j];
    // physical chunk = (lane>>4) ^ ((fr>>1)&3).
    const int fr = lane & 15;
    const int roff = fr * 32 + (((lane >> 4) ^ ((fr >> 1) & 3)) << 3);
    const int aBase = wr * 4096 + roff;  // wr*128 rows * 32 elems
    const int bBase = wc * 2048 + roff;  // wc*64 rows * 32 elems

    floatx4 acc[8][4] = {};

    // ---- prologue: kh0(0), kh1(0), kh0(1) staged in FIFO order ----
    STAGE(gA, sA, 0);             // A kh0 t0 -> slot 0
    STAGE(gB, sB, 0);
    STAGE(gA + 32, sA, 8192);     // A kh1 t0 -> slot 1
    STAGE(gB + 32, sB, 8192);
    STAGE(gA + 64, sA, 16384);    // A kh0 t1 -> slot 2
    STAGE(gB + 64, sB, 16384);
    asm volatile("s_waitcnt vmcnt(8)" ::: "memory");  // kh0(0) landed
    __builtin_amdgcn_s_barrier();

    for (int t = 0; t < NT; ++t) {
        const int cs = (t & 1) ? 16384 : 0;   // this tile's kh0 slot (elems)
        const int ns = cs ^ 16384;            // next tile's kh0 slot
        const __bf16* sA0 = sA + cs;
        const __bf16* sA1 = sA + cs + 8192;
        const __bf16* sB0 = sB + cs;
        const __bf16* sB1 = sB + cs + 8192;

        bf16x8 af0[4], af1[4], bfr[4];

        // ======== Phase A: kh0 x (mh0+mh1) ; stage kh1(t+1) pair ========
        if (t + 1 < NT) {
            STAGE(gA + (size_t)(t + 1) * 64 + 32, sA, ns + 8192);
            STAGE(gB + (size_t)(t + 1) * 64 + 32, sB, ns + 8192);
        }
#pragma unroll
        for (int i = 0; i < 4; ++i)
            af0[i] = *(const bf16x8*)(sA0 + aBase + i * 512);
#pragma unroll
        for (int j = 0; j < 4; ++j)
            bfr[j] = *(const bf16x8*)(sB0 + bBase + j * 512);
#pragma unroll
        for (int i = 0; i < 4; ++i)
            af1[i] = *(const bf16x8*)(sA0 + aBase + 2048 + i * 512);
        __builtin_amdgcn_s_setprio(1);
#pragma unroll
        for (int i = 0; i < 4; ++i)
#pragma unroll
            for (int j = 0; j < 4; ++j)
                acc[i][j] = __builtin_amdgcn_mfma_f32_16x16x32_bf16(
                    af0[i], bfr[j], acc[i][j], 0, 0, 0);
#pragma unroll
        for (int i = 0; i < 4; ++i)
#pragma unroll
            for (int j = 0; j < 4; ++j)
                acc[i + 4][j] = __builtin_amdgcn_mfma_f32_16x16x32_bf16(
                    af1[i], bfr[j], acc[i + 4][j], 0, 0, 0);
        __builtin_amdgcn_s_setprio(0);
        // drain kh1(t) (staged in phase A of t-1 / prologue)
        if (t + 1 < NT)
            asm volatile("s_waitcnt vmcnt(8)" ::: "memory");
        else
            asm volatile("s_waitcnt vmcnt(0)" ::: "memory");
        __builtin_amdgcn_s_barrier();

        // ======== Phase B: kh1 x (mh0+mh1) ; stage kh0(t+2) pair ========
        if (t + 2 < NT) {
            STAGE(gA + (size_t)(t + 2) * 64, sA, cs);
            STAGE(gB + (size_t)(t + 2) * 64, sB, cs);
        }
#pragma unroll
        for (int i = 0; i < 4; ++i)
            af0[i] = *(const bf16x8*)(sA1 + aBase + i * 512);
#pragma unroll
        for (int j = 0; j < 4; ++j)
            bfr[j] = *(const bf16x8*)(sB1 + bBase + j * 512);
#pragma unroll
        for (int i = 0; i < 4; ++i)
            af1[i] = *(const bf16x8*)(sA1 + aBase + 2048 + i * 512);
        __builtin_amdgcn_s_setprio(1);
#pragma unroll
        for (int i = 0; i < 4; ++i)
#pragma unroll
            for (int j = 0; j < 4; ++j)
                acc[i][j] = __builtin_amdgcn_mfma_f32_16x16x32_bf16(
                    af0[i], bfr[j], acc[i][j], 0, 0, 0);
#pragma unroll
        for (int i = 0; i < 4; ++i)
#pragma unroll
            for (int j = 0; j < 4; ++j)
                acc[i + 4][j] = __builtin_amdgcn_mfma_f32_16x16x32_bf16(
                    af1[i], bfr[j], acc[i + 4][j], 0, 0, 0);
        __builtin_amdgcn_s_setprio(0);
        // drain kh0(t+1) (staged in phase B of t-1 / prologue)
        if (t + 2 < NT)
            asm volatile("s_waitcnt vmcnt(8)" ::: "memory");
        else if (t + 1 < NT)
            asm volatile("s_waitcnt vmcnt(4)" ::: "memory");
        else
            asm volatile("s_waitcnt vmcnt(0)" ::: "memory");
        __builtin_amdgcn_s_barrier();
    }

    // Epilogue. C/D layout: col = lane&15, row = (lane>>4)*4 + reg
    const int crow = (lane >> 4) * 4;
    const int ccol = lane & 15;
#pragma unroll
    for (int j = 0; j < 4; ++j) {
        const int n = n0 + wc * 64 + j * 16 + ccol;
        const float bv = bias[n];
#pragma unroll
        for (int i = 0; i < 8; ++i) {
            const int m = m0 + wr * 128 + i * 16 + crow;
            float* cp = C + (size_t)m * N_DIM + n;
#pragma unroll
            for (int r = 0; r < 4; ++r)
                __builtin_nontemporal_store(acc[i][j][r] + bv,
                                            cp + (size_t)r * N_DIM);
        }
    }
}

extern "C" void kernel_launch(void* const* d_in, const int* in_sizes, int n_in,
                              void* d_out, int out_size, void* d_ws, size_t ws_size,
                              hipStream_t stream) {
    const float* x    = (const float*)d_in[0];   // [4,2048,4096] fp32
    const float* cb   = (const float*)d_in[1];   // [4096,8] fp32
    const int*   idx  = (const int*)d_in[2];     // [2M]
    const float* bias = (const float*)d_in[3];   // [4096]
    float* out = (float*)d_out;                  // [4,2048,4096] fp32

    // workspace layout: W_bf16 (32 MB) | x_bf16 (64 MB)
    __bf16* Wb = (__bf16*)d_ws;
    __bf16* Xb = (__bf16*)((char*)d_ws + (size_t)N_DIM * K_DIM * sizeof(__bf16));

    prep_kernel<<<W_WGS + X_WGS, 256, 0, stream>>>(
        cb, idx, (uint4*)Wb, (const floatx4*)x, (uintx2*)Xb);

    dim3 grid(M_DIM / BM * (N_DIM / BN));  // 512 WGs, XCD-chunked in-kernel
    gemm_bt_kernel<<<grid, 512, 0, stream>>>(Xb, Wb, bias, out);
}

// Round 6
// 457.008 us; speedup vs baseline: 1.1187x; 1.0076x over previous
//
#include <hip/hip_runtime.h>
#include <stdint.h>

// y[8192,4096] = x[8192,4096] @ W[4096,4096]^T + bias
// W from codebook[4096,8] gathered by indices[2M].
// R10: cross-phase register ping-pong. Each phase issues the NEXT phase's
//      fragment ds_reads between its two 16-MFMA half-clusters; ordering is
//      enforced by register reuse (fA/fB consumed by half0/half1, then
//      reloaded). LDS pipe and matrix pipe now run concurrently per wave.
//      Fence schedule shifted one phase earlier: every phase ends vmcnt(4)
//      (publishes the unit preread 1.5 phases after issue); tails 0.
//      Registers unchanged (12 live frags + 128 AGPR acc).

#define M_DIM 8192
#define N_DIM 4096
#define K_DIM 4096
#define BM 256
#define BN 256
#define BK 64
#define NT (K_DIM / BK)                       // 64 K-tiles
#define NUM_W_BLOCKS 2097152                  // 4096*4096/8
#define W_WGS (NUM_W_BLOCKS / 256)            // 8192 WGs for W dequant
#define X_WGS ((M_DIM * K_DIM / 4) / 256)     // 32768 WGs, one float4/thread

typedef __attribute__((ext_vector_type(8))) __bf16 bf16x8;
typedef __attribute__((ext_vector_type(4))) float floatx4;
typedef __attribute__((ext_vector_type(2))) unsigned int uintx2;

// fp32 -> bf16 round-to-nearest-even (finite inputs)
__device__ __forceinline__ unsigned int f2bf(float f) {
    unsigned int u = __builtin_bit_cast(unsigned int, f);
    u += 0x7fffu + ((u >> 16) & 1u);
    return u >> 16;
}

// ------------- fused prep: W dequant-gather + x fp32->bf16 -------------
__global__ __launch_bounds__(256) void prep_kernel(
    const float* __restrict__ cb, const int* __restrict__ idx,
    uint4* __restrict__ W, const floatx4* __restrict__ x,
    uintx2* __restrict__ xb) {
    const int wg = blockIdx.x;
    if (wg < W_WGS) {
        const int b = wg * 256 + threadIdx.x;
        const int id = __builtin_nontemporal_load(idx + b);
        const float4* s = (const float4*)(cb + ((size_t)id << 3));
        const float4 a = s[0];
        const float4 c = s[1];
        uint4 o;
        o.x = f2bf(a.x) | (f2bf(a.y) << 16);
        o.y = f2bf(a.z) | (f2bf(a.w) << 16);
        o.z = f2bf(c.x) | (f2bf(c.y) << 16);
        o.w = f2bf(c.z) | (f2bf(c.w) << 16);
        W[b] = o;
    } else {
        const size_t t = (size_t)(wg - W_WGS) * 256 + threadIdx.x;
        const floatx4 a = __builtin_nontemporal_load(x + t);
        uintx2 o;
        o.x = f2bf(a.x) | (f2bf(a.y) << 16);
        o.y = f2bf(a.z) | (f2bf(a.w) << 16);
        xb[t] = o;
    }
}

// ---------------- async global -> LDS, 16B per lane ----------------
__device__ __forceinline__ void async_copy16(const __bf16* g, __bf16* s) {
    __builtin_amdgcn_global_load_lds(
        (const __attribute__((address_space(1))) unsigned int*)(uintptr_t)g,
        (__attribute__((address_space(3))) unsigned int*)(uintptr_t)s,
        16, 0, 0);
}

// Stage one unit = one operand k-half (256 rows x 32 bf16 = 16 KiB):
// 2 global_load_lds per thread (rows 0-127, rows 128-255).
#define STAGE(gsrc, arr, slotElems)                                        \
    do {                                                                   \
        async_copy16((gsrc), (arr) + (slotElems) + wave512);               \
        async_copy16((gsrc) + (size_t)128 * K_DIM,                         \
                     (arr) + (slotElems) + 4096 + wave512);                \
    } while (0)

// ---------------- GEMM: C[M][N] = A[M][K] * B[N][K]^T + bias ----------------
// 512 threads = 8 waves (2M x 4N); wave owns 128x64 output = acc[8][4] f32x4.
// LDS: per operand a 4-slot ring of 16KiB k-half units: slot = (t&1)*2 + kh.
// 2 phases per K-tile, register ping-pong:
//   entry: fA = af0(cur), fB = bfr(cur)  [preread during previous phase]
//   phase = [STAGE next unit pair] [fC <- af1(cur)] [MFMA half0: fA x fB]
//           [fA <- af0(next)] [MFMA half1: fC x fB] [fB <- bfr(next)]
//           [vmcnt(4)] [s_barrier]
// Publication: unit preread in phase P was staged in phase P-2 and drained
// by the vmcnt(4) at end of P-1 (cover ~2 phases >> HBM latency).
// Preread-WAR: each preread is consumed by the NEXT phase's MFMA (so it
// completes before that phase's closing barrier); the overwriting STAGE of
// its slot is issued only after that barrier.
__global__ __launch_bounds__(512, 2) void gemm_bt_kernel(
    const __bf16* __restrict__ A,   // [M][K] bf16
    const __bf16* __restrict__ B,   // [N][K] bf16
    const float* __restrict__ bias, // [N]
    float* __restrict__ C) {        // [M][N] fp32
    __shared__ __align__(16) __bf16 sA[4 * 8192];   // 64 KiB
    __shared__ __align__(16) __bf16 sB[4 * 8192];   // 64 KiB

    const int tid = threadIdx.x;
    const int wave = tid >> 6;
    const int lane = tid & 63;
    const int wr = wave >> 2;            // 0..1  (M half of tile)
    const int wc = wave & 3;             // 0..3  (N quarter of tile)

    // T1: XCD-chunked mapping (verified R6: FETCH 670->197 MB).
    const int flat = blockIdx.x;
    const int xcd = flat & 7;
    const int q = flat >> 3;             // 0..63
    const int half = q >> 5;             // 0..1
    const int sq = q & 31;
    const int m0 = ((xcd & 3) * 8 + half * 4 + (sq & 3)) * BM;
    const int n0 = ((xcd >> 2) * 8 + (sq >> 2)) * BN;

    // staging: thread t covers row = t>>2 (+128 for 2nd half), phys chunk t&3;
    // fetch logical chunk c = p ^ ((row>>1)&3) (involution, invariant +16/+128)
    const int srow = tid >> 2;
    const int schunk = ((tid & 3) ^ ((srow >> 1) & 3)) << 3;
    const __bf16* gA = A + (size_t)(m0 + srow) * K_DIM + schunk;
    const __bf16* gB = B + (size_t)(n0 + srow) * K_DIM + schunk;
    const int wave512 = wave << 9;

    // fragment reads: lane holds X[row = base + fr][k = (lane>>4)*8 + j];
    // physical chunk = (lane>>4) ^ ((fr>>1)&3).
    const int fr = lane & 15;
    const int roff = fr * 32 + (((lane >> 4) ^ ((fr >> 1) & 3)) << 3);
    const int aBase = wr * 4096 + roff;  // wr*128 rows * 32 elems
    const int bBase = wc * 2048 + roff;  // wc*64 rows * 32 elems

    floatx4 acc[8][4] = {};
    bf16x8 fA[4], fB[4], fC[4];

    // ---- prologue: kh0(0), kh1(0), kh0(1) staged in FIFO order ----
    STAGE(gA, sA, 0);             // A kh0 t0 -> slot 0
    STAGE(gB, sB, 0);
    STAGE(gA + 32, sA, 8192);     // A kh1 t0 -> slot 1
    STAGE(gB + 32, sB, 8192);
    STAGE(gA + 64, sA, 16384);    // A kh0 t1 -> slot 2
    STAGE(gB + 64, sB, 16384);
    // kh0(0) AND kh1(0) landed (kh1(0) is preread mid-phase-A(0))
    asm volatile("s_waitcnt vmcnt(4)" ::: "memory");
    __builtin_amdgcn_s_barrier();
    // preload entry fragments for phase A(0): af0/bfr of kh0(0)
#pragma unroll
    for (int i = 0; i < 4; ++i)
        fA[i] = *(const bf16x8*)(sA + aBase + i * 512);
#pragma unroll
    for (int j = 0; j < 4; ++j)
        fB[j] = *(const bf16x8*)(sB + bBase + j * 512);

    for (int t = 0; t < NT; ++t) {
        const int cs = (t & 1) ? 16384 : 0;   // this tile's kh0 slot (elems)
        const int ns = cs ^ 16384;            // next tile's kh0 slot
        const __bf16* pA0 = sA + cs;          // kh0(t)
        const __bf16* pB0 = sB + cs;
        const __bf16* pA1 = sA + cs + 8192;   // kh1(t)
        const __bf16* pB1 = sB + cs + 8192;
        const __bf16* nA0 = sA + ns;          // kh0(t+1)
        const __bf16* nB0 = sB + ns;

        // ===== Phase A: compute kh0(t); preread kh1(t); stage kh1(t+1) =====
        if (t + 1 < NT) {
            STAGE(gA + (size_t)(t + 1) * 64 + 32, sA, ns + 8192);
            STAGE(gB + (size_t)(t + 1) * 64 + 32, sB, ns + 8192);
        }
#pragma unroll
        for (int i = 0; i < 4; ++i)           // af1(kh0): consumed by half1
            fC[i] = *(const bf16x8*)(pA0 + aBase + 2048 + i * 512);
        __builtin_amdgcn_s_setprio(1);
#pragma unroll
        for (int i = 0; i < 4; ++i)
#pragma unroll
            for (int j = 0; j < 4; ++j)
                acc[i][j] = __builtin_amdgcn_mfma_f32_16x16x32_bf16(
                    fA[i], fB[j], acc[i][j], 0, 0, 0);
        __builtin_amdgcn_s_setprio(0);
#pragma unroll
        for (int i = 0; i < 4; ++i)           // af0(kh1): WAR on half0
            fA[i] = *(const bf16x8*)(pA1 + aBase + i * 512);
        __builtin_amdgcn_s_setprio(1);
#pragma unroll
        for (int i = 0; i < 4; ++i)
#pragma unroll
            for (int j = 0; j < 4; ++j)
                acc[i + 4][j] = __builtin_amdgcn_mfma_f32_16x16x32_bf16(
                    fC[i], fB[j], acc[i + 4][j], 0, 0, 0);
        __builtin_amdgcn_s_setprio(0);
#pragma unroll
        for (int j = 0; j < 4; ++j)           // bfr(kh1): WAR on half1
            fB[j] = *(const bf16x8*)(pB1 + bBase + j * 512);
        // publish kh0(t+1): outstanding = [kh0(t+1)4, kh1(t+1)4] -> 4
        if (t + 1 < NT)
            asm volatile("s_waitcnt vmcnt(4)" ::: "memory");
        else
            asm volatile("s_waitcnt vmcnt(0)" ::: "memory");  // no-op tail
        __builtin_amdgcn_s_barrier();

        // ===== Phase B: compute kh1(t); preread kh0(t+1); stage kh0(t+2) ====
        if (t + 2 < NT) {
            STAGE(gA + (size_t)(t + 2) * 64, sA, cs);
            STAGE(gB + (size_t)(t + 2) * 64, sB, cs);
        }
#pragma unroll
        for (int i = 0; i < 4; ++i)           // af1(kh1): consumed by half1
            fC[i] = *(const bf16x8*)(pA1 + aBase + 2048 + i * 512);
        __builtin_amdgcn_s_setprio(1);
#pragma unroll
        for (int i = 0; i < 4; ++i)
#pragma unroll
            for (int j = 0; j < 4; ++j)
                acc[i][j] = __builtin_amdgcn_mfma_f32_16x16x32_bf16(
                    fA[i], fB[j], acc[i][j], 0, 0, 0);
        __builtin_amdgcn_s_setprio(0);
        if (t + 1 < NT) {
#pragma unroll
            for (int i = 0; i < 4; ++i)       // af0(kh0,t+1)
                fA[i] = *(const bf16x8*)(nA0 + aBase + i * 512);
        }
        __builtin_amdgcn_s_setprio(1);
#pragma unroll
        for (int i = 0; i < 4; ++i)
#pragma unroll
            for (int j = 0; j < 4; ++j)
                acc[i + 4][j] = __builtin_amdgcn_mfma_f32_16x16x32_bf16(
                    fC[i], fB[j], acc[i + 4][j], 0, 0, 0);
        __builtin_amdgcn_s_setprio(0);
        if (t + 1 < NT) {
#pragma unroll
            for (int j = 0; j < 4; ++j)       // bfr(kh0,t+1)
                fB[j] = *(const bf16x8*)(nB0 + bBase + j * 512);
        }
        // publish kh1(t+1): outstanding = [kh1(t+1)4, kh0(t+2)4] -> 4
        if (t + 2 < NT)
            asm volatile("s_waitcnt vmcnt(4)" ::: "memory");
        else
            asm volatile("s_waitcnt vmcnt(0)" ::: "memory");  // t=NT-2: publish
        __builtin_amdgcn_s_barrier();                          // kh1(NT-1)
    }

    // Epilogue. C/D layout: col = lane&15, row = (lane>>4)*4 + reg
    const int crow = (lane >> 4) * 4;
    const int ccol = lane & 15;
#pragma unroll
    for (int j = 0; j < 4; ++j) {
        const int n = n0 + wc * 64 + j * 16 + ccol;
        const float bv = bias[n];
#pragma unroll
        for (int i = 0; i < 8; ++i) {
            const int m = m0 + wr * 128 + i * 16 + crow;
            float* cp = C + (size_t)m * N_DIM + n;
#pragma unroll
            for (int r = 0; r < 4; ++r)
                __builtin_nontemporal_store(acc[i][j][r] + bv,
                                            cp + (size_t)r * N_DIM);
        }
    }
}

extern "C" void kernel_launch(void* const* d_in, const int* in_sizes, int n_in,
                              void* d_out, int out_size, void* d_ws, size_t ws_size,
                              hipStream_t stream) {
    const float* x    = (const float*)d_in[0];   // [4,2048,4096] fp32
    const float* cb   = (const float*)d_in[1];   // [4096,8] fp32
    const int*   idx  = (const int*)d_in[2];     // [2M]
    const float* bias = (const float*)d_in[3];   // [4096]
    float* out = (float*)d_out;                  // [4,2048,4096] fp32

    // workspace layout: W_bf16 (32 MB) | x_bf16 (64 MB)
    __bf16* Wb = (__bf16*)d_ws;
    __bf16* Xb = (__bf16*)((char*)d_ws + (size_t)N_DIM * K_DIM * sizeof(__bf16));

    prep_kernel<<<W_WGS + X_WGS, 256, 0, stream>>>(
        cb, idx, (uint4*)Wb, (const floatx4*)x, (uintx2*)Xb);

    dim3 grid(M_DIM / BM * (N_DIM / BN));  // 512 WGs, XCD-chunked in-kernel
    gemm_bt_kernel<<<grid, 512, 0, stream>>>(Xb, Wb, bias, out);
}